// Round 8
// baseline (149.769 us; speedup 1.0000x reference)
//
#include <hip/hip_runtime.h>
#include <hip/hip_bf16.h>

// PAM module: B=4, N=4096 (64x64), C=64.
// out[b,n,c] = gamma * sum_m softmax_row(q@k^T)[m,n] * v[m,c] + x[b,n,c]
//
// bf16 MFMA; energy recomputed. log2e folded into Wq/bq; softmax normalizer
// folded into QK MFMA C-init (lr = -log2(rowsum)); P built in registers
// (K=16 PV MFMA identity), truncation bf16 pack.
//  k1 : fused: zero sbuf (w3==0), W->W^T bf16 in-block, projections;
//       ALL global stores coalesced via LDS staging. grid 768.
//  k2 : partial rowsums, n-split 4; waves n-distributed. grid 1024.
//  r2 : lr = -log2(s) ; out <- x
//  k3 : out += gamma * exp2(e'+lr) @ v ; m-split 4 blocks, 2x2 wave split
//       (waves split m AND n -> halved LDS broadcast reads). grid 1024.

typedef __attribute__((ext_vector_type(8))) short short8;
typedef __attribute__((ext_vector_type(4))) short short4b;
typedef __attribute__((ext_vector_type(4))) float f32x4;
typedef __attribute__((ext_vector_type(4))) unsigned int u32x4;
typedef __attribute__((ext_vector_type(2))) unsigned int u32x2;

#define DEV static __device__ __forceinline__
#define LOG2E 1.4426950408889634f

DEV unsigned short f2bf(float f) {
    __hip_bfloat16 h = __float2bfloat16(f);
    return __builtin_bit_cast(unsigned short, h);
}
DEV unsigned int pack2(float lo, float hi) {
    return (unsigned int)f2bf(lo) | ((unsigned int)f2bf(hi) << 16);
}
DEV unsigned int pack2t(float lo, float hi) {   // truncation-pack (P>=0, no NaN)
    unsigned int ul = __builtin_bit_cast(unsigned int, lo);
    unsigned int uh = __builtin_bit_cast(unsigned int, hi);
    return (uh & 0xffff0000u) | (ul >> 16);
}
DEV f32x4 MFMA32(short8 a, short8 b, f32x4 c) {
    return __builtin_amdgcn_mfma_f32_16x16x32_bf16(a, b, c, 0, 0, 0);
}
DEV f32x4 MFMA16(short4b a, short4b b, f32x4 c) {
#if __has_builtin(__builtin_amdgcn_mfma_f32_16x16x16_bf16)
    return __builtin_amdgcn_mfma_f32_16x16x16_bf16(a, b, c, 0, 0, 0);
#else
    return __builtin_amdgcn_mfma_f32_16x16x16bf16_1k(a, b, c, 0, 0, 0);
#endif
}
DEV float EXP2(float x) {
#if __has_builtin(__builtin_amdgcn_exp2f)
    return __builtin_amdgcn_exp2f(x);
#else
    return exp2f(x);
#endif
}

// ws layout (bytes)
#define OFF_Q    0u          // [16384][64] bf16 = 2 MB  (q' = log2e * (xWq+bq))
#define OFF_K    2097152u    // [16384][64] bf16 = 2 MB
#define OFF_VT   4194304u    // [4][64][4096] bf16 = 2 MB
#define OFF_S    6291456u    // [16384] f32 = 64 KB (row sums, atomic)
#define OFF_LR   6356992u    // [16384] f32 = 64 KB (lr = -log2 s)

// ---------------- k1: fused zero-s + W^T + projections (grid 768) ----------------
__global__ __launch_bounds__(256) void k1_proj(const float* __restrict__ x,
                                               const float* __restrict__ Wq,
                                               const float* __restrict__ bq,
                                               const float* __restrict__ Wk,
                                               const float* __restrict__ bk,
                                               const float* __restrict__ Wv,
                                               const float* __restrict__ bv,
                                               unsigned short* __restrict__ qg,
                                               unsigned short* __restrict__ kg,
                                               unsigned short* __restrict__ vtg,
                                               float* __restrict__ sbuf) {
    __shared__ __align__(16) char XT[8192];     // [64 m][128B c] swz
    __shared__ __align__(16) char WT1[8192];    // [64 f][128B c] swz
    __shared__ __align__(16) char OT[9216];     // [64][72 shorts] output staging
    int t = threadIdx.x, blk = blockIdx.x;
    int w3 = blk >> 8, rb = blk & 255;

    if (w3 == 0 && t < 64) sbuf[rb * 64 + t] = 0.0f;   // zero rowsum buffer

    {   // stage x tile (fp32 -> bf16, swizzled)
        int m = t >> 2, q4 = t & 3;
        const f32x4* xs = (const f32x4*)(x + (size_t)(rb * 64 + m) * 64 + q4 * 16);
        f32x4 fa = xs[0], f2 = xs[1], fc = xs[2], fd = xs[3];
        u32x4 u0 = { pack2(fa[0],fa[1]), pack2(fa[2],fa[3]), pack2(f2[0],f2[1]), pack2(f2[2],f2[3]) };
        u32x4 u1 = { pack2(fc[0],fc[1]), pack2(fc[2],fc[3]), pack2(fd[0],fd[1]), pack2(fd[2],fd[3]) };
        int sw = (m & 7) << 4;
        *(u32x4*)(XT + m * 128 + ((q4 * 32) ^ sw)) = u0;
        *(u32x4*)(XT + m * 128 + ((q4 * 32 + 16) ^ sw)) = u1;
    }
    const float* W = (w3 == 0) ? Wq : (w3 == 1) ? Wk : Wv;
    float wscale = (w3 == 0) ? LOG2E : 1.0f;
    {   // stage W^T directly from global (transpose + scale)  wt[f][c] = W[c][f]*s
        int f = t >> 2, q4 = t & 3;
        unsigned int u[8];
        #pragma unroll
        for (int i = 0; i < 8; ++i) {
            float lo = W[(size_t)(q4 * 16 + 2 * i) * 64 + f] * wscale;
            float hi = W[(size_t)(q4 * 16 + 2 * i + 1) * 64 + f] * wscale;
            u[i] = pack2(lo, hi);
        }
        u32x4 u0 = { u[0], u[1], u[2], u[3] }, u1 = { u[4], u[5], u[6], u[7] };
        int sw = (f & 7) << 4;
        *(u32x4*)(WT1 + f * 128 + ((q4 * 32) ^ sw)) = u0;
        *(u32x4*)(WT1 + f * 128 + ((q4 * 32 + 16) ^ sw)) = u1;
    }
    __syncthreads();

    int lane = t & 63, wid = t >> 6, g = lane >> 4, ln = lane & 15;
    int arow = wid * 16 + ln;
    short8 a0 = *(const short8*)(XT + arow * 128 + ((16 * g) ^ ((arow & 7) << 4)));
    short8 a1 = *(const short8*)(XT + arow * 128 + ((64 + 16 * g) ^ ((arow & 7) << 4)));
    const float* bias = (w3 == 0) ? bq : (w3 == 1) ? bk : bv;

    unsigned short* ot = (unsigned short*)OT;
    #pragma unroll
    for (int fb = 0; fb < 4; ++fb) {
        int frow = fb * 16 + ln;
        short8 b0 = *(const short8*)(WT1 + frow * 128 + ((16 * g) ^ ((frow & 7) << 4)));
        short8 b1 = *(const short8*)(WT1 + frow * 128 + ((64 + 16 * g) ^ ((frow & 7) << 4)));
        f32x4 acc = {0.f, 0.f, 0.f, 0.f};
        acc = MFMA32(a0, b0, acc);
        acc = MFMA32(a1, b1, acc);
        float bval = bias[frow] * wscale;
        int mloc = wid * 16 + 4 * g;
        if (w3 < 2) {   // q,k: OT[m][c]
            #pragma unroll
            for (int r = 0; r < 4; ++r)
                ot[(mloc + r) * 72 + frow] = f2bf(acc[r] + bval);
        } else {        // v: OT[c][m] (transposed)
            #pragma unroll
            for (int r = 0; r < 4; ++r)
                ot[frow * 72 + mloc + r] = f2bf(acc[r] + bval);
        }
    }
    __syncthreads();
    {   // coalesced global write
        int rr = t >> 2, mq = t & 3;
        u32x4 u0 = *(const u32x4*)(OT + rr * 144 + mq * 32);
        u32x4 u1 = *(const u32x4*)(OT + rr * 144 + mq * 32 + 16);
        if (w3 < 2) {   // row rr = local m
            unsigned short* dst = ((w3 == 0) ? qg : kg) + (size_t)(rb * 64 + rr) * 64 + mq * 16;
            *(u32x4*)(dst) = u0;
            *(u32x4*)(dst + 8) = u1;
        } else {        // row rr = c ; cols = local m -> vtg[b][c][n]
            int b = rb >> 6, n0 = (rb & 63) * 64;
            unsigned short* dst = vtg + (size_t)b * 262144 + (size_t)rr * 4096 + n0 + mq * 16;
            *(u32x4*)(dst) = u0;
            *(u32x4*)(dst + 8) = u1;
        }
    }
}

// ---------------- k2: partial row sums, n-distributed waves ----------------
// grid 1024: blk = b*256 + ns*64 + mb. Block owns 64 m; wave pins A-frags for
// ALL 64 m (32 VGPR) and computes only its own 2 n-subtiles per 128-n chunk.
__global__ __launch_bounds__(256, 4) void k2_rowsum(const unsigned short* __restrict__ qg,
                                                    const unsigned short* __restrict__ kg,
                                                    float* __restrict__ sbuf) {
    __shared__ __align__(16) char KD[2][16384];   // [128 n][128B c] swz
    int t = threadIdx.x, blk = blockIdx.x;
    int b = blk >> 8, ns = (blk >> 6) & 3, mb = blk & 63;
    int m0 = mb * 64, nbase = ns * 1024;
    int lane = t & 63, wid = t >> 6, g = lane >> 4, ln = lane & 15;

    short8 a[4][2];
    {
        const unsigned short* qr = qg + (size_t)(b * 4096 + m0 + ln) * 64;
        #pragma unroll
        for (int mi = 0; mi < 4; ++mi) {
            a[mi][0] = *(const short8*)(qr + mi * 1024 + 8 * g);
            a[mi][1] = *(const short8*)(qr + mi * 1024 + 32 + 8 * g);
        }
    }
    int kr = t >> 1, kh = t & 1, ksw = (kr & 7) << 4;
    const unsigned short* kbase = kg + (size_t)(b * 4096 + nbase) * 64;
    {
        const u32x4* s = (const u32x4*)(kbase + (size_t)kr * 64 + kh * 32);
        u32x4 u0 = s[0], u1 = s[1], u2 = s[2], u3 = s[3];
        char* d = KD[0] + kr * 128;
        *(u32x4*)(d + ((kh * 64 +  0) ^ ksw)) = u0;
        *(u32x4*)(d + ((kh * 64 + 16) ^ ksw)) = u1;
        *(u32x4*)(d + ((kh * 64 + 32) ^ ksw)) = u2;
        *(u32x4*)(d + ((kh * 64 + 48) ^ ksw)) = u3;
    }
    __syncthreads();

    f32x4 z = {0.f, 0.f, 0.f, 0.f};
    f32x4 acc[4] = {z, z, z, z};
    int buf = 0;
    for (int nc = 0; nc < 8; ++nc) {
        int nn = (nc < 7) ? nc + 1 : nc;
        const u32x4* s = (const u32x4*)(kbase + (size_t)(nn * 128 + kr) * 64 + kh * 32);
        u32x4 p0 = s[0], p1 = s[1], p2 = s[2], p3 = s[3];
        const char* kt = KD[buf];
        #pragma unroll
        for (int j = 0; j < 2; ++j) {
            int brow = (2 * wid + j) * 16 + ln, bsw = (brow & 7) << 4;
            short8 kb0 = *(const short8*)(kt + brow * 128 + ((16 * g) ^ bsw));
            short8 kb1 = *(const short8*)(kt + brow * 128 + ((64 + 16 * g) ^ bsw));
            #pragma unroll
            for (int mi = 0; mi < 4; ++mi) {
                f32x4 e = MFMA32(a[mi][1], kb1, MFMA32(a[mi][0], kb0, z));
                acc[mi][0] += EXP2(e[0]); acc[mi][1] += EXP2(e[1]);
                acc[mi][2] += EXP2(e[2]); acc[mi][3] += EXP2(e[3]);
            }
        }
        char* d = KD[buf ^ 1] + kr * 128;
        *(u32x4*)(d + ((kh * 64 +  0) ^ ksw)) = p0;
        *(u32x4*)(d + ((kh * 64 + 16) ^ ksw)) = p1;
        *(u32x4*)(d + ((kh * 64 + 32) ^ ksw)) = p2;
        *(u32x4*)(d + ((kh * 64 + 48) ^ ksw)) = p3;
        __syncthreads();
        buf ^= 1;
    }
    #pragma unroll
    for (int mi = 0; mi < 4; ++mi) {
        #pragma unroll
        for (int msk = 1; msk < 16; msk <<= 1) {
            acc[mi][0] += __shfl_xor(acc[mi][0], msk);
            acc[mi][1] += __shfl_xor(acc[mi][1], msk);
            acc[mi][2] += __shfl_xor(acc[mi][2], msk);
            acc[mi][3] += __shfl_xor(acc[mi][3], msk);
        }
    }
    if (ln == 0) {
        #pragma unroll
        for (int mi = 0; mi < 4; ++mi) {
            float* base = sbuf + b * 4096 + m0 + mi * 16 + 4 * g;
            unsafeAtomicAdd(base + 0, acc[mi][0]);
            unsafeAtomicAdd(base + 1, acc[mi][1]);
            unsafeAtomicAdd(base + 2, acc[mi][2]);
            unsafeAtomicAdd(base + 3, acc[mi][3]);
        }
    }
}

// ---------------- r2: lr = -log2(s) ; out <- x ----------------
__global__ __launch_bounds__(256) void r2_init(const float* __restrict__ sbuf,
                                               float* __restrict__ lrbuf,
                                               const float* __restrict__ x,
                                               float* __restrict__ outp) {
    int tid = blockIdx.x * 256 + threadIdx.x;   // grid 1024
    if (tid < 16384) lrbuf[tid] = -__log2f(sbuf[tid]);
    f32x4 v = *(const f32x4*)(x + 4 * (size_t)tid);
    *(f32x4*)(outp + 4 * (size_t)tid) = v;
}

// ---------------- k3: out += gamma * exp2(e'+lr) @ v  (2x2 wave split) ----------------
// grid 1024: blk = b*256 + ms*64 + nb. Wave (wm,wn): wm picks m-half of each
// 64-m chunk (2 of 4 s-subblocks), wn picks n-half (2 pinned k subtiles).
// Halves per-wave LDS broadcast reads vs all-waves-read-all.
__global__ __launch_bounds__(256, 4) void k3_out(const unsigned short* __restrict__ qg,
                                                 const unsigned short* __restrict__ kg,
                                                 const unsigned short* __restrict__ vtg,
                                                 const float* __restrict__ lrbuf,
                                                 const float* __restrict__ gamma,
                                                 float* __restrict__ outp) {
    __shared__ __align__(16) char QD[2][8192];   // [64 m][128B c] swz
    __shared__ __align__(16) char VD[2][8192];   // [64 c][128B m] swz
    int t = threadIdx.x, blk = blockIdx.x;
    int b = blk >> 8, ms = (blk >> 6) & 3, nb = blk & 63;
    int n0 = nb * 64, mbase = ms * 1024;
    int lane = t & 63, wid = t >> 6, g = lane >> 4, ln = lane & 15;
    int wm = wid >> 1, wn = wid & 1;

    // pinned k B-frags for this wave's 2 n-subtiles
    short8 kb[2][2];
    #pragma unroll
    for (int jj = 0; jj < 2; ++jj) {
        const unsigned short* krp = kg + (size_t)(b * 4096 + n0 + (2 * wn + jj) * 16 + ln) * 64;
        kb[jj][0] = *(const short8*)(krp + 8 * g);
        kb[jj][1] = *(const short8*)(krp + 32 + 8 * g);
    }

    int row = t >> 2, q4 = t & 3, sw = (row & 7) << 4;
    const unsigned short* qbase = qg + (size_t)(b * 4096 + mbase + row) * 64 + q4 * 16;
    const unsigned short* vbase = vtg + (size_t)b * 262144 + (size_t)row * 4096 + mbase + q4 * 16;
    {   // chunk 0
        u32x4 q0 = *(const u32x4*)(qbase);
        u32x4 q1 = *(const u32x4*)(qbase + 8);
        u32x4 v0 = *(const u32x4*)(vbase);
        u32x4 v1 = *(const u32x4*)(vbase + 8);
        *(u32x4*)(QD[0] + row * 128 + ((q4 * 32) ^ sw)) = q0;
        *(u32x4*)(QD[0] + row * 128 + ((q4 * 32 + 16) ^ sw)) = q1;
        *(u32x4*)(VD[0] + row * 128 + ((q4 * 32) ^ sw)) = v0;
        *(u32x4*)(VD[0] + row * 128 + ((q4 * 32 + 16) ^ sw)) = v1;
    }
    const float* lrb = lrbuf + b * 4096 + mbase + 4 * g;
    f32x4 lcA = *(const f32x4*)(lrb + (2 * wm) * 16);
    f32x4 lcB = *(const f32x4*)(lrb + (2 * wm + 1) * 16);
    __syncthreads();

    f32x4 z = {0.f, 0.f, 0.f, 0.f};
    f32x4 oacc[2][4] = { {z, z, z, z}, {z, z, z, z} };   // [jj][fb]
    int buf = 0;
    for (int mc = 0; mc < 16; ++mc) {
        int nx = (mc < 15) ? mc + 1 : mc;
        u32x4 qp0 = *(const u32x4*)(qbase + (size_t)nx * 64 * 64);
        u32x4 qp1 = *(const u32x4*)(qbase + (size_t)nx * 64 * 64 + 8);
        u32x4 vp0 = *(const u32x4*)(vbase + nx * 64);
        u32x4 vp1 = *(const u32x4*)(vbase + nx * 64 + 8);
        f32x4 lnA = *(const f32x4*)(lrb + nx * 64 + (2 * wm) * 16);
        f32x4 lnB = *(const f32x4*)(lrb + nx * 64 + (2 * wm + 1) * 16);

        const char* qt = QD[buf];
        const char* vt = VD[buf];
        #pragma unroll
        for (int sub = 0; sub < 2; ++sub) {
            int s = 2 * wm + sub;
            int qrow = s * 16 + ln, qsw = (qrow & 7) << 4;
            short8 as0 = *(const short8*)(qt + qrow * 128 + ((16 * g) ^ qsw));
            short8 as1 = *(const short8*)(qt + qrow * 128 + ((64 + 16 * g) ^ qsw));
            // vT frags for this m-subblock (shared across jj)
            short4b vb0, vb1, vb2, vb3;
            {
                int so = s * 32 + g * 8;
                vb0 = *(const short4b*)(vt + (0 * 16 + ln) * 128 + (so ^ (((0 * 16 + ln) & 7) << 4)));
                vb1 = *(const short4b*)(vt + (1 * 16 + ln) * 128 + (so ^ (((1 * 16 + ln) & 7) << 4)));
                vb2 = *(const short4b*)(vt + (2 * 16 + ln) * 128 + (so ^ (((2 * 16 + ln) & 7) << 4)));
                vb3 = *(const short4b*)(vt + (3 * 16 + ln) * 128 + (so ^ (((3 * 16 + ln) & 7) << 4)));
            }
            f32x4 lv = sub ? lcB : lcA;
            #pragma unroll
            for (int jj = 0; jj < 2; ++jj) {
                f32x4 e = MFMA32(as1, kb[jj][1], MFMA32(as0, kb[jj][0], lv));
                float p0 = EXP2(e[0]), p1 = EXP2(e[1]), p2 = EXP2(e[2]), p3 = EXP2(e[3]);
                u32x2 pw = { pack2t(p0, p1), pack2t(p2, p3) };
                short4b pa = __builtin_bit_cast(short4b, pw);
                oacc[jj][0] = MFMA16(pa, vb0, oacc[jj][0]);
                oacc[jj][1] = MFMA16(pa, vb1, oacc[jj][1]);
                oacc[jj][2] = MFMA16(pa, vb2, oacc[jj][2]);
                oacc[jj][3] = MFMA16(pa, vb3, oacc[jj][3]);
            }
        }
        *(u32x4*)(QD[buf ^ 1] + row * 128 + ((q4 * 32) ^ sw)) = qp0;
        *(u32x4*)(QD[buf ^ 1] + row * 128 + ((q4 * 32 + 16) ^ sw)) = qp1;
        *(u32x4*)(VD[buf ^ 1] + row * 128 + ((q4 * 32) ^ sw)) = vp0;
        *(u32x4*)(VD[buf ^ 1] + row * 128 + ((q4 * 32 + 16) ^ sw)) = vp1;
        lcA = lnA; lcB = lnB;
        __syncthreads();
        buf ^= 1;
    }

    float gm = gamma[0];
    #pragma unroll
    for (int jj = 0; jj < 2; ++jj) {
        int nr = b * 4096 + n0 + (2 * wn + jj) * 16 + 4 * g;
        #pragma unroll
        for (int fb = 0; fb < 4; ++fb) {
            #pragma unroll
            for (int r = 0; r < 4; ++r)
                unsafeAtomicAdd(outp + (size_t)(nr + r) * 64 + fb * 16 + ln, gm * oacc[jj][fb][r]);
        }
    }
}

extern "C" void kernel_launch(void* const* d_in, const int* in_sizes, int n_in,
                              void* d_out, int out_size, void* d_ws, size_t ws_size,
                              hipStream_t stream) {
    const float* x  = (const float*)d_in[0];
    const float* Wq = (const float*)d_in[1];
    const float* bq = (const float*)d_in[2];
    const float* Wk = (const float*)d_in[3];
    const float* bk = (const float*)d_in[4];
    const float* Wv = (const float*)d_in[5];
    const float* bv = (const float*)d_in[6];
    const float* gm = (const float*)d_in[7];
    char* ws = (char*)d_ws;
    float* outp = (float*)d_out;

    unsigned short* qg  = (unsigned short*)(ws + OFF_Q);
    unsigned short* kg  = (unsigned short*)(ws + OFF_K);
    unsigned short* vtg = (unsigned short*)(ws + OFF_VT);
    float* sbuf         = (float*)(ws + OFF_S);
    float* lrbuf        = (float*)(ws + OFF_LR);

    k1_proj<<<768, 256, 0, stream>>>(x, Wq, bq, Wk, bk, Wv, bv, qg, kg, vtg, sbuf);
    k2_rowsum<<<1024, 256, 0, stream>>>(qg, kg, sbuf);
    r2_init<<<1024, 256, 0, stream>>>(sbuf, lrbuf, x, outp);
    k3_out<<<1024, 256, 0, stream>>>(qg, kg, vtg, lrbuf, gm, outp);
}